// Round 4
// baseline (1273.745 us; speedup 1.0000x reference)
//
#include <hip/hip_runtime.h>
#include <hip/hip_bf16.h>
#include <cstdint>

typedef __hip_bfloat16 bf16;
typedef unsigned int uint;
typedef unsigned short ushort;

#define DEVI __device__ __forceinline__

DEVI float blo(uint u){ return __uint_as_float(u << 16); }
DEVI float bhi(uint u){ return __uint_as_float(u & 0xffff0000u); }
// f32 -> bf16 RTNE (finite inputs)
DEVI ushort f2b(float x){ uint u = __float_as_uint(x); uint r = (u + 0x7fffu + ((u >> 16) & 1u)) >> 16; return (ushort)r; }
DEVI uint pack2(float a, float b){ return (uint)f2b(a) | ((uint)f2b(b) << 16); }
DEVI float b2f(ushort h){ return __uint_as_float((uint)h << 16); }

typedef short bf16x8 __attribute__((ext_vector_type(8)));
typedef float f32x4  __attribute__((ext_vector_type(4)));

// 16-lane row sum via DPP row_ror 1/2/4/8 (pure VALU, no LDS pipe).
DEVI float row16_sum(float x){
  int y;
  y = __builtin_amdgcn_update_dpp(0, __float_as_int(x), 0x121, 0xF, 0xF, true); x += __int_as_float(y);
  y = __builtin_amdgcn_update_dpp(0, __float_as_int(x), 0x122, 0xF, 0xF, true); x += __int_as_float(y);
  y = __builtin_amdgcn_update_dpp(0, __float_as_int(x), 0x124, 0xF, 0xF, true); x += __int_as_float(y);
  y = __builtin_amdgcn_update_dpp(0, __float_as_int(x), 0x128, 0xF, 0xF, true); x += __int_as_float(y);
  return x;
}

// generic pack body: S[K][C] f32 -> B-fragment-ordered bf16 hi/lo pairs.
// b = ks*ctn + ct; lane l holds S[k][c], k = ks*32 + (l>>4)*8 + j, c = ct*16 + (l&15).
DEVI void frag_pack_body(const float* __restrict__ S, uint4* __restrict__ D, int C, int ctn, int b, int l){
  const int ks = b / ctn, ct = b - ks*ctn;
  const int kb = ks*32 + (l >> 4)*8;
  const int c  = ct*16 + (l & 15);
  ushort hi[8], lo[8];
  #pragma unroll
  for (int j = 0; j < 8; ++j){
    float wv = S[(size_t)(kb + j)*C + c];
    ushort hh = f2b(wv);
    hi[j] = hh;
    lo[j] = f2b(wv - b2f(hh));
  }
  uint4 H, L;
  H.x = (uint)hi[0] | ((uint)hi[1] << 16);
  H.y = (uint)hi[2] | ((uint)hi[3] << 16);
  H.z = (uint)hi[4] | ((uint)hi[5] << 16);
  H.w = (uint)hi[6] | ((uint)hi[7] << 16);
  L.x = (uint)lo[0] | ((uint)lo[1] << 16);
  L.y = (uint)lo[2] | ((uint)lo[3] << 16);
  L.z = (uint)lo[4] | ((uint)lo[5] << 16);
  L.w = (uint)lo[6] | ((uint)lo[7] << 16);
  D[((size_t)b*2 + 0)*64 + l] = H;
  D[((size_t)b*2 + 1)*64 + l] = L;
}

// ---------------- PREP1: build_M | build_bias | Wo-pack | count_edges  (independent work fused)
__global__ __launch_bounds__(256) void prep1(
    const float* __restrict__ Wq, const float* __restrict__ Wk,
    const float* __restrict__ bq, const float* __restrict__ bk,
    const float* __restrict__ Wo, const int* __restrict__ av,
    float* __restrict__ Mb, float* __restrict__ cvec, float* __restrict__ uvec,
    float* __restrict__ sv, uint4* __restrict__ Wp, int* __restrict__ counts, int E)
{
  __shared__ float WkL[128*33];
  __shared__ float WqL[16*33];
  const int b = blockIdx.x, t = threadIdx.x;
  if (b < 64){
    // ---- build_M: M[h][p][m] = sum_j Wq[h][p][j]*Wk[h][m][j], stored Mb[p][h*128+m]
    const int h = b >> 3, pg = b & 7, p0 = pg*16;
    const float* wk = Wk + (size_t)h*16384;
    const float* wq = Wq + ((size_t)h*128 + p0)*128;
    const int m = t & 127, half = t >> 7;
    float acc[8] = {0,0,0,0,0,0,0,0};
    for (int jc = 0; jc < 4; ++jc){
      __syncthreads();
      #pragma unroll
      for (int i = 0; i < 4; ++i){
        int g = t + 256*i;
        int mm = g >> 3, j0 = (g & 7)*4;
        float4 v = *(const float4*)(wk + mm*128 + jc*32 + j0);
        float* d = &WkL[mm*33 + j0];
        d[0] = v.x; d[1] = v.y; d[2] = v.z; d[3] = v.w;
      }
      {
        int e = t*2;
        int pr = e >> 5, jj = e & 31;
        float2 v = *(const float2*)(wq + pr*128 + jc*32 + jj);
        WqL[pr*33 + jj] = v.x; WqL[pr*33 + jj + 1] = v.y;
      }
      __syncthreads();
      for (int j = 0; j < 32; ++j){
        float wkv = WkL[m*33 + j];
        #pragma unroll
        for (int r = 0; r < 8; ++r)
          acc[r] = fmaf(WqL[(half*8 + r)*33 + j], wkv, acc[r]);
      }
    }
    #pragma unroll
    for (int r = 0; r < 8; ++r)
      Mb[(size_t)(p0 + half*8 + r)*1024 + h*128 + m] = acc[r];
  } else if (b < 72){
    // ---- build_bias
    if (t < 128){
      int h = b - 64, m = t;
      const float* wkr = Wk + ((size_t)h*128 + m)*128;
      const float* wqr = Wq + ((size_t)h*128 + m)*128;
      const float* bqr = bq + h*128;
      const float* bkr = bk + h*128;
      float c = 0.f, u = 0.f;
      for (int j = 0; j < 128; ++j){
        c = fmaf(wkr[j], bqr[j], c);
        u = fmaf(wqr[j], bkr[j], u);
      }
      cvec[h*128 + m] = c;
      uvec[h*128 + m] = u;
      if (m == 0){
        float s = 0.f;
        for (int j = 0; j < 128; ++j) s = fmaf(bqr[j], bkr[j], s);
        sv[h] = s;
      }
    }
  } else if (b < 328){
    // ---- Wo pack: K=1024, C=128, ctn=8
    if (t < 64) frag_pack_body(Wo, Wp, 128, 8, b - 72, t);
  } else {
    // ---- count_edges
    int e = (b - 328)*256 + t;
    if (e < E) atomicAdd(&counts[av[e]], 1);
  }
}

// ---------------- PREP2: scan_offsets(256-thr) | Mb-pack | scatter_aq
__global__ __launch_bounds__(256) void prep2(
    const int* __restrict__ counts, int* __restrict__ offsets, int N,
    const float* __restrict__ Mb, uint4* __restrict__ Mp,
    const int* __restrict__ pk, const int* __restrict__ pv,
    const float* __restrict__ ast, float* __restrict__ aq,
    ushort* __restrict__ aqh, ushort* __restrict__ aql, int n_map)
{
  __shared__ int pa[256];
  __shared__ int pb[256];
  const int b = blockIdx.x, t = threadIdx.x;
  if (b == 0){
    // ---- exclusive scan of counts -> offsets (one block, 256 threads)
    const int CH = (N + 255) >> 8;
    int b0 = t*CH, e0 = b0 + CH;
    if (b0 > N) b0 = N;
    if (e0 > N) e0 = N;
    int s = 0;
    for (int i = b0; i < e0; ++i) s += counts[i];
    pa[t] = s;
    __syncthreads();
    int* src = pa; int* dst = pb;
    for (int off = 1; off < 256; off <<= 1){
      int v = src[t];
      if (t >= off) v += src[t - off];
      __syncthreads();
      dst[t] = v;
      __syncthreads();
      int* tmp = src; src = dst; dst = tmp;
    }
    int run = src[t] - s;
    for (int i = b0; i < e0; ++i){ offsets[i] = run; run += counts[i]; }
    if (t == 255) offsets[N] = src[255];
  } else if (b < 257){
    // ---- Mb pack: K=128, C=1024, ctn=64
    if (t < 64) frag_pack_body(Mb, Mp, 1024, 64, b - 1, t);
  } else {
    // ---- scatter_aq, 4 mappings per block
    int i = (b - 257)*4 + (t >> 6);
    int lane = t & 63;
    if (i < n_map){
      int k = pk[i], src = pv[i];
      float2 v = *(const float2*)(ast + (size_t)src*128 + 2*lane);
      *(float2*)(aq + (size_t)k*128 + 2*lane) = v;
      ushort h0 = f2b(v.x), h1 = f2b(v.y);
      ushort l0 = f2b(v.x - b2f(h0)), l1 = f2b(v.y - b2f(h1));
      *(uint*)(aqh + (size_t)k*128 + 2*lane) = (uint)h0 | ((uint)h1 << 16);
      *(uint*)(aql + (size_t)k*128 + 2*lane) = (uint)l0 | ((uint)l1 << 16);
    }
  }
}

// ---------------- PREP3: qb_kernel | fill_edges
__global__ __launch_bounds__(256) void prep3(
    const float* __restrict__ aq, const float* __restrict__ uvec, const float* __restrict__ sv,
    float* __restrict__ qb, const int* __restrict__ av, const int* __restrict__ akey,
    const int* __restrict__ offsets, int* __restrict__ cursor, int* __restrict__ ridx,
    int N, int E)
{
  const int b = blockIdx.x, t = threadIdx.x;
  const int nqb = (N + 3) >> 2;
  if (b < nqb){
    int n = b*4 + (t >> 6);
    int lane = t & 63;
    if (n < N){
      int h = lane >> 3, g = lane & 7;
      const float* ar = aq + (size_t)n*128 + g*16;
      const float* ur = uvec + h*128 + g*16;
      float dot = 0.f;
      #pragma unroll
      for (int k = 0; k < 16; ++k) dot = fmaf(ar[k], ur[k], dot);
      dot += __shfl_xor(dot, 1);
      dot += __shfl_xor(dot, 2);
      dot += __shfl_xor(dot, 4);
      if (g == 0) qb[(size_t)n*8 + h] = dot + sv[h];
    }
  } else {
    int e = (b - nqb)*256 + t;
    if (e < E){
      int seg = av[e];
      int pos = offsets[seg] + atomicAdd(&cursor[seg], 1);
      ridx[pos] = akey[e];
    }
  }
}

// ---------------- K3: qt = aq*Mb + cvec via split-bf16 MFMA (3 passes).
__global__ __launch_bounds__(256, 1) void qt_mfma(const ushort* __restrict__ aqh, const ushort* __restrict__ aql,
                                                  const uint4* __restrict__ Mp, const float* __restrict__ cvec,
                                                  bf16* __restrict__ qt, int N){
  const int l = threadIdx.x & 63, w = threadIdx.x >> 6;
  const int lr = l & 15, lk = l >> 4;
  const int r0 = blockIdx.x*128 + w*32;
  int ra = r0 + lr;      if (ra > N-1) ra = N-1;
  int rb = r0 + 16 + lr; if (rb > N-1) rb = N-1;

  bf16x8 Ah0[4], Al0[4], Ah1[4], Al1[4];
  #pragma unroll
  for (int ks = 0; ks < 4; ++ks){
    Ah0[ks] = *(const bf16x8*)(aqh + (size_t)ra*128 + lk*8 + ks*32);
    Al0[ks] = *(const bf16x8*)(aql + (size_t)ra*128 + lk*8 + ks*32);
    Ah1[ks] = *(const bf16x8*)(aqh + (size_t)rb*128 + lk*8 + ks*32);
    Al1[ks] = *(const bf16x8*)(aql + (size_t)rb*128 + lk*8 + ks*32);
  }
  const uint4* pw = Mp + l;

  bf16x8 Ba[8], Bb[8];   // [ks*2 + {hi,lo}]
  auto LDB = [&](int ct, bf16x8* B){
    #pragma unroll
    for (int ks = 0; ks < 4; ++ks){
      const uint4* q = pw + ((size_t)(ks*64 + ct)*2)*64;
      B[ks*2]   = *(const bf16x8*)q;
      B[ks*2+1] = *(const bf16x8*)(q + 64);
    }
  };
  auto DO = [&](int ct, bf16x8* B){
    f32x4 a0 = {0.f,0.f,0.f,0.f}, a1 = {0.f,0.f,0.f,0.f};
    #pragma unroll
    for (int ks = 0; ks < 4; ++ks){
      a0 = __builtin_amdgcn_mfma_f32_16x16x32_bf16(Ah0[ks], B[2*ks],   a0, 0, 0, 0);
      a1 = __builtin_amdgcn_mfma_f32_16x16x32_bf16(Ah1[ks], B[2*ks],   a1, 0, 0, 0);
      a0 = __builtin_amdgcn_mfma_f32_16x16x32_bf16(Al0[ks], B[2*ks],   a0, 0, 0, 0);
      a1 = __builtin_amdgcn_mfma_f32_16x16x32_bf16(Al1[ks], B[2*ks],   a1, 0, 0, 0);
      a0 = __builtin_amdgcn_mfma_f32_16x16x32_bf16(Ah0[ks], B[2*ks+1], a0, 0, 0, 0);
      a1 = __builtin_amdgcn_mfma_f32_16x16x32_bf16(Ah1[ks], B[2*ks+1], a1, 0, 0, 0);
    }
    const int cc = ct*16 + lr;
    const float bv = cvec[cc];
    #pragma unroll
    for (int i = 0; i < 4; ++i){
      int rr0 = r0 + lk*4 + i;
      if (rr0 < N) ((ushort*)qt)[(size_t)rr0*1024 + cc] = f2b(a0[i] + bv);
      int rr1 = r0 + 16 + lk*4 + i;
      if (rr1 < N) ((ushort*)qt)[(size_t)rr1*1024 + cc] = f2b(a1[i] + bv);
    }
  };

  LDB(0, Ba);
  for (int ct = 0; ct < 64; ct += 2){
    LDB(ct + 1, Bb);
    DO(ct, Ba);
    if (ct + 2 < 64) LDB(ct + 2, Ba);
    DO(ct + 1, Bb);
  }
}

// ---------------- K6: per-segment attention v4. 1 wave = 1 segment.
// - edge list vector-loaded once per 64-edge chunk (rlist[lane]); per-pair row indices via
//   v_readlane -> SGPR -> saddr global loads: zero VALU addressing, zero index-load latency.
// - 4 pair-buffers (8 rows, 16 VMEM in flight) held in registers; launch_bounds(256,4)
//   gives the 128-VGPR budget so the compiler cannot collapse the pipeline.
// - DPP row16 reduce, both heads per 16-lane group (4x request dup, 2 instrs/edge).
__global__ __launch_bounds__(256, 4) void seg_attn(
    const bf16* __restrict__ qt, const float* __restrict__ qb,
    const int* __restrict__ offsets, const int* __restrict__ ridx,
    const float* __restrict__ ast, bf16* __restrict__ ho, int N)
{
  const int wid  = threadIdx.x >> 6;
  const int lane = threadIdx.x & 63;
  const int n = blockIdx.x*4 + wid;
  if (n >= N) return;
  const int beg = __builtin_amdgcn_readfirstlane(offsets[n]);
  const int end = __builtin_amdgcn_readfirstlane(offsets[n+1]);
  const int deg = end - beg;
  const int grp = lane >> 4, d4 = lane & 15;
  const int h0 = 2*grp, h1 = 2*grp + 1;
  const int vo = d4*2;                   // float4 index within a 128-f32 row
  const int* rp = ridx + beg;

  // chunk-0 edge-index list: issue FIRST (it gates the prefetch pipeline)
  int idx0 = lane < deg ? lane : (deg - 1);
  int rlist0 = (deg > 0) ? rp[idx0] : 0;

  // q fragment loads (independent; overlap with rlist load)
  const ushort* qtp = (const ushort*)qt + (size_t)n*1024 + d4*8;
  const uint4 Qa = *(const uint4*)(qtp + h0*128);
  const uint4 Qb = *(const uint4*)(qtp + h1*128);
  const float SC = 0.12751744886681336f;           // log2(e)/sqrt(128)
  const float qs0 = qb[(size_t)n*8 + h0] * SC;
  const float qs1 = qb[(size_t)n*8 + h1] * SC;
  const float4 q0lo = make_float4(blo(Qa.x), bhi(Qa.x), blo(Qa.y), bhi(Qa.y));
  const float4 q0hi = make_float4(blo(Qa.z), bhi(Qa.z), blo(Qa.w), bhi(Qa.w));
  const float4 q1lo = make_float4(blo(Qb.x), bhi(Qb.x), blo(Qb.y), bhi(Qb.y));
  const float4 q1hi = make_float4(blo(Qb.z), bhi(Qb.z), blo(Qb.w), bhi(Qb.w));

  float den0 = 0.f, den1 = 0.f;
  float4 x0lo = make_float4(0,0,0,0), x0hi = x0lo, x1lo = x0lo, x1hi = x0lo;

#define ISSUE(Pa0, Pa1, Pb0, Pb1, pidx) do { \
    int pi_ = (pidx); pi_ = pi_ > 31 ? 31 : pi_; \
    int rA_ = __builtin_amdgcn_readlane(rlist, 2*pi_); \
    int rB_ = __builtin_amdgcn_readlane(rlist, 2*pi_ + 1); \
    const float4* pA_ = (const float4*)(ast + (size_t)(uint)rA_*128) + vo; \
    const float4* pB_ = (const float4*)(ast + (size_t)(uint)rB_*128) + vo; \
    Pa0 = pA_[0]; Pa1 = pA_[1]; Pb0 = pB_[0]; Pb1 = pB_[1]; } while(0)

#define C1(A0, A1) do { \
    float s0, s1; \
    s0 = A0.x*q0lo.x; s0 = fmaf(A0.y, q0lo.y, s0); s0 = fmaf(A0.z, q0lo.z, s0); s0 = fmaf(A0.w, q0lo.w, s0); \
    s0 = fmaf(A1.x, q0hi.x, s0); s0 = fmaf(A1.y, q0hi.y, s0); s0 = fmaf(A1.z, q0hi.z, s0); s0 = fmaf(A1.w, q0hi.w, s0); \
    s1 = A0.x*q1lo.x; s1 = fmaf(A0.y, q1lo.y, s1); s1 = fmaf(A0.z, q1lo.z, s1); s1 = fmaf(A0.w, q1lo.w, s1); \
    s1 = fmaf(A1.x, q1hi.x, s1); s1 = fmaf(A1.y, q1hi.y, s1); s1 = fmaf(A1.z, q1hi.z, s1); s1 = fmaf(A1.w, q1hi.w, s1); \
    s0 = row16_sum(s0); s1 = row16_sum(s1); \
    const float p0 = exp2f(fmaf(s0, SC, qs0)); \
    const float p1 = exp2f(fmaf(s1, SC, qs1)); \
    den0 += p0; den1 += p1; \
    x0lo.x = fmaf(p0, A0.x, x0lo.x); x0lo.y = fmaf(p0, A0.y, x0lo.y); \
    x0lo.z = fmaf(p0, A0.z, x0lo.z); x0lo.w = fmaf(p0, A0.w, x0lo.w); \
    x0hi.x = fmaf(p0, A1.x, x0hi.x); x0hi.y = fmaf(p0, A1.y, x0hi.y); \
    x0hi.z = fmaf(p0, A1.z, x0hi.z); x0hi.w = fmaf(p0, A1.w, x0hi.w); \
    x1lo.x = fmaf(p1, A0.x, x1lo.x); x1lo.y = fmaf(p1, A0.y, x1lo.y); \
    x1lo.z = fmaf(p1, A0.z, x1lo.z); x1lo.w = fmaf(p1, A0.w, x1lo.w); \
    x1hi.x = fmaf(p1, A1.x, x1hi.x); x1hi.y = fmaf(p1, A1.y, x1hi.y); \
    x1hi.z = fmaf(p1, A1.z, x1hi.z); x1hi.w = fmaf(p1, A1.w, x1hi.w); \
  } while(0)

  for (int c0 = 0; c0 < deg; c0 += 64){
    int ecnt = deg - c0; if (ecnt > 64) ecnt = 64;
    const int np = (ecnt + 1) >> 1;
    int rlist;
    if (c0 == 0){
      rlist = rlist0;
    } else {
      int ii = c0 + lane; if (ii >= deg) ii = deg - 1;
      rlist = rp[ii];
    }
    float4 P0a0, P0a1, P0b0, P0b1;
    float4 P1a0, P1a1, P1b0, P1b1;
    float4 P2a0, P2a1, P2b0, P2b1;
    float4 P3a0, P3a1, P3b0, P3b1;
    ISSUE(P0a0, P0a1, P0b0, P0b1, 0);
    if (np > 1) ISSUE(P1a0, P1a1, P1b0, P1b1, 1);
    if (np > 2) ISSUE(P2a0, P2a1, P2b0, P2b1, 2);
    if (np > 3) ISSUE(P3a0, P3a1, P3b0, P3b1, 3);

    int p = 0;
    for (; p + 4 < np; p += 4){
      C1(P0a0, P0a1); C1(P0b0, P0b1);
      if (p + 4 < np) ISSUE(P0a0, P0a1, P0b0, P0b1, p + 4);
      C1(P1a0, P1a1); C1(P1b0, P1b1);
      if (p + 5 < np) ISSUE(P1a0, P1a1, P1b0, P1b1, p + 5);
      C1(P2a0, P2a1); C1(P2b0, P2b1);
      if (p + 6 < np) ISSUE(P2a0, P2a1, P2b0, P2b1, p + 6);
      C1(P3a0, P3a1); C1(P3b0, P3b1);
      if (p + 7 < np) ISSUE(P3a0, P3a1, P3b0, P3b1, p + 7);
    }
    const int rem = np - p;   // 1..4
    {              C1(P0a0, P0a1); if (2*p + 1 < ecnt) C1(P0b0, P0b1); }
    if (rem > 1){  C1(P1a0, P1a1); if (2*p + 3 < ecnt) C1(P1b0, P1b1); }
    if (rem > 2){  C1(P2a0, P2a1); if (2*p + 5 < ecnt) C1(P2b0, P2b1); }
    if (rem > 3){  C1(P3a0, P3a1); if (2*p + 7 < ecnt) C1(P3b0, P3b1); }
  }
#undef C1
#undef ISSUE

  const float r0v = (deg > 0) ? (1.f / den0) : 0.f;
  const float r1v = (deg > 0) ? (1.f / den1) : 0.f;

  uint4 o0, o1;
  o0.x = pack2(x0lo.x*r0v, x0lo.y*r0v); o0.y = pack2(x0lo.z*r0v, x0lo.w*r0v);
  o0.z = pack2(x0hi.x*r0v, x0hi.y*r0v); o0.w = pack2(x0hi.z*r0v, x0hi.w*r0v);
  o1.x = pack2(x1lo.x*r1v, x1lo.y*r1v); o1.y = pack2(x1lo.z*r1v, x1lo.w*r1v);
  o1.z = pack2(x1hi.x*r1v, x1hi.y*r1v); o1.w = pack2(x1hi.z*r1v, x1hi.w*r1v);
  ushort* hb = (ushort*)ho + (size_t)n*1024 + d4*8;
  *(uint4*)(hb + h0*128) = o0;
  *(uint4*)(hb + h1*128) = o1;
}

// ---------------- K5: out[n][c] = sum_k ho[n][k]*Wo[k][c] + bo[c]  via bf16 MFMA, split-Wo.
__global__ __launch_bounds__(256, 1) void out_mfma(const bf16* __restrict__ ho, const uint4* __restrict__ Wp,
                                                   const float* __restrict__ bo, float* __restrict__ out, int N){
  const int l = threadIdx.x & 63, w = threadIdx.x >> 6;
  const int lr = l & 15, lk = l >> 4;
  const int r0 = blockIdx.x*128 + w*32;
  int ra = r0 + lr;      if (ra > N-1) ra = N-1;
  int rb = r0 + 16 + lr; if (rb > N-1) rb = N-1;
  const bf16* pa = ho + (size_t)ra*1024 + lk*8;
  const bf16* pb = ho + (size_t)rb*1024 + lk*8;
  const uint4* pw = Wp + l;

  f32x4 acc[2][8];
  #pragma unroll
  for (int i = 0; i < 2; ++i)
    #pragma unroll
    for (int c = 0; c < 8; ++c)
      #pragma unroll
      for (int j = 0; j < 4; ++j) acc[i][c][j] = 0.f;

  bf16x8 Aa[2], Ab[2], Ba[16], Bb[16];

  auto LD = [&](int ks, bf16x8* A, bf16x8* B){
    A[0] = *(const bf16x8*)(pa + ks*32);
    A[1] = *(const bf16x8*)(pb + ks*32);
    const uint4* q = pw + (size_t)ks*1024;
    #pragma unroll
    for (int u = 0; u < 16; ++u) B[u] = *(const bf16x8*)(q + (size_t)u*64);
  };
  auto MM = [&](bf16x8* A, bf16x8* B){
    #pragma unroll
    for (int c = 0; c < 8; ++c){
      acc[0][c] = __builtin_amdgcn_mfma_f32_16x16x32_bf16(A[0], B[2*c],   acc[0][c], 0, 0, 0);
      acc[1][c] = __builtin_amdgcn_mfma_f32_16x16x32_bf16(A[1], B[2*c],   acc[1][c], 0, 0, 0);
      acc[0][c] = __builtin_amdgcn_mfma_f32_16x16x32_bf16(A[0], B[2*c+1], acc[0][c], 0, 0, 0);
      acc[1][c] = __builtin_amdgcn_mfma_f32_16x16x32_bf16(A[1], B[2*c+1], acc[1][c], 0, 0, 0);
    }
  };

  LD(0, Aa, Ba);
  for (int ks = 0; ks < 32; ks += 2){
    LD(ks + 1, Ab, Bb);
    MM(Aa, Ba);
    if (ks + 2 < 32) LD(ks + 2, Aa, Ba);
    MM(Ab, Bb);
  }

  #pragma unroll
  for (int c = 0; c < 8; ++c){
    float bv = bo[c*16 + lr];
    #pragma unroll
    for (int rt = 0; rt < 2; ++rt){
      #pragma unroll
      for (int i = 0; i < 4; ++i){
        int rr = r0 + rt*16 + lk*4 + i;
        if (rr < N) out[(size_t)rr*128 + c*16 + lr] = acc[rt][c][i] + bv;
      }
    }
  }
}

extern "C" void kernel_launch(void* const* d_in, const int* in_sizes, int n_in,
                              void* d_out, int out_size, void* d_ws, size_t ws_size,
                              hipStream_t stream) {
  const float* ast = (const float*)d_in[0];
  const float* Wq  = (const float*)d_in[1];
  const float* bq  = (const float*)d_in[2];
  const float* Wk  = (const float*)d_in[3];
  const float* bk  = (const float*)d_in[4];
  const float* Wo  = (const float*)d_in[5];
  const float* bo  = (const float*)d_in[6];
  const int* ast_key   = (const int*)d_in[7];
  const int* ast_value = (const int*)d_in[8];
  const int* pdg_key   = (const int*)d_in[9];
  const int* pdg_value = (const int*)d_in[10];
  const int E     = in_sizes[7];
  const int n_map = in_sizes[9];
  const int N     = out_size / 128;
  float* out = (float*)d_out;   // reference output dtype is float32

  char* w = (char*)d_ws;
  auto carve = [&](size_t bytes)->char*{
    char* p = w; w += (bytes + 255) & ~size_t(255); return p;
  };
  // NOTE: aq/aqh/aql adjacent (one memset); counts/cursor adjacent (one memset).
  bf16*  qt      = (bf16*) carve((size_t)N*1024*2);
  float* aq      = (float*)carve((size_t)N*128*4);
  ushort* aqh    = (ushort*)carve((size_t)N*128*2);
  ushort* aql    = (ushort*)carve((size_t)N*128*2);
  float* Mb      = (float*)carve((size_t)128*1024*4);
  float* cvec    = (float*)carve(1024*4);
  float* uvec    = (float*)carve(1024*4);
  float* sv      = (float*)carve(8*4);
  float* qb      = (float*)carve((size_t)N*8*4);
  int*   counts  = (int*)  carve((size_t)N*4);
  int*   cursor  = (int*)  carve((size_t)N*4);
  int*   offsets = (int*)  carve((size_t)(N+1)*4);
  int*   ridx    = (int*)  carve((size_t)E*4);
  bf16*  ho      = (bf16*) carve((size_t)N*1024*2);
  uint4* Wp      = (uint4*)carve((size_t)256*2*64*16);   // 512 KB packed WoHi/WoLo frags
  uint4* Mp      = (uint4*)carve((size_t)256*2*64*16);   // 512 KB packed MbHi/MbLo frags
  (void)ws_size; (void)n_in;

  hipMemsetAsync(aq,     0, (size_t)N*128*8, stream);    // aq + aqh + aql (contiguous)
  hipMemsetAsync(counts, 0, (size_t)N*8, stream);        // counts + cursor (contiguous)

  const int nb_cnt  = (E + 255)/256;
  const int nb_sca  = (n_map + 3)/4;
  const int nb_qb   = (N + 3)/4;

  prep1<<<328 + nb_cnt, 256, 0, stream>>>(Wq, Wk, bq, bk, Wo, ast_value, Mb, cvec, uvec, sv, Wp, counts, E);
  prep2<<<257 + nb_sca, 256, 0, stream>>>(counts, offsets, N, Mb, Mp, pdg_key, pdg_value, ast, aq, aqh, aql, n_map);
  qt_mfma<<<(N + 127)/128, 256, 0, stream>>>(aqh, aql, Mp, cvec, qt, N);
  prep3<<<nb_qb + nb_cnt, 256, 0, stream>>>(aq, uvec, sv, qb, ast_value, ast_key, offsets, cursor, ridx, N, E);
  seg_attn<<<(N + 3)/4, 256, 0, stream>>>(qt, qb, offsets, ridx, ast, ho, N);
  out_mfma<<<(N + 127)/128, 256, 0, stream>>>(ho, Wp, bo, out, N);
}

// Round 5
// 694.651 us; speedup vs baseline: 1.8336x; 1.8336x over previous
//
#include <hip/hip_runtime.h>
#include <hip/hip_bf16.h>
#include <cstdint>

typedef __hip_bfloat16 bf16;
typedef unsigned int uint;
typedef unsigned short ushort;

#define DEVI __device__ __forceinline__

DEVI float blo(uint u){ return __uint_as_float(u << 16); }
DEVI float bhi(uint u){ return __uint_as_float(u & 0xffff0000u); }
// f32 -> bf16 RTNE (finite inputs)
DEVI ushort f2b(float x){ uint u = __float_as_uint(x); uint r = (u + 0x7fffu + ((u >> 16) & 1u)) >> 16; return (ushort)r; }
DEVI uint pack2(float a, float b){ return (uint)f2b(a) | ((uint)f2b(b) << 16); }
DEVI float b2f(ushort h){ return __uint_as_float((uint)h << 16); }

typedef short bf16x8 __attribute__((ext_vector_type(8)));
typedef float f32x4  __attribute__((ext_vector_type(4)));

// 16-lane row sum via DPP row_ror 1/2/4/8 (pure VALU, no LDS pipe).
DEVI float row16_sum(float x){
  int y;
  y = __builtin_amdgcn_update_dpp(0, __float_as_int(x), 0x121, 0xF, 0xF, true); x += __int_as_float(y);
  y = __builtin_amdgcn_update_dpp(0, __float_as_int(x), 0x122, 0xF, 0xF, true); x += __int_as_float(y);
  y = __builtin_amdgcn_update_dpp(0, __float_as_int(x), 0x124, 0xF, 0xF, true); x += __int_as_float(y);
  y = __builtin_amdgcn_update_dpp(0, __float_as_int(x), 0x128, 0xF, 0xF, true); x += __int_as_float(y);
  return x;
}

// generic pack body: S[K][C] f32 -> B-fragment-ordered bf16 hi/lo pairs.
// b = ks*ctn + ct; lane l holds S[k][c], k = ks*32 + (l>>4)*8 + j, c = ct*16 + (l&15).
DEVI void frag_pack_body(const float* __restrict__ S, uint4* __restrict__ D, int C, int ctn, int b, int l){
  const int ks = b / ctn, ct = b - ks*ctn;
  const int kb = ks*32 + (l >> 4)*8;
  const int c  = ct*16 + (l & 15);
  ushort hi[8], lo[8];
  #pragma unroll
  for (int j = 0; j < 8; ++j){
    float wv = S[(size_t)(kb + j)*C + c];
    ushort hh = f2b(wv);
    hi[j] = hh;
    lo[j] = f2b(wv - b2f(hh));
  }
  uint4 H, L;
  H.x = (uint)hi[0] | ((uint)hi[1] << 16);
  H.y = (uint)hi[2] | ((uint)hi[3] << 16);
  H.z = (uint)hi[4] | ((uint)hi[5] << 16);
  H.w = (uint)hi[6] | ((uint)hi[7] << 16);
  L.x = (uint)lo[0] | ((uint)lo[1] << 16);
  L.y = (uint)lo[2] | ((uint)lo[3] << 16);
  L.z = (uint)lo[4] | ((uint)lo[5] << 16);
  L.w = (uint)lo[6] | ((uint)lo[7] << 16);
  D[((size_t)b*2 + 0)*64 + l] = H;
  D[((size_t)b*2 + 1)*64 + l] = L;
}

// ---------------- PREP1: build_M | build_bias | Wo-pack | count_edges  (independent work fused)
__global__ __launch_bounds__(256) void prep1(
    const float* __restrict__ Wq, const float* __restrict__ Wk,
    const float* __restrict__ bq, const float* __restrict__ bk,
    const float* __restrict__ Wo, const int* __restrict__ av,
    float* __restrict__ Mb, float* __restrict__ cvec, float* __restrict__ uvec,
    float* __restrict__ sv, uint4* __restrict__ Wp, int* __restrict__ counts, int E)
{
  __shared__ float WkL[128*33];
  __shared__ float WqL[16*33];
  const int b = blockIdx.x, t = threadIdx.x;
  if (b < 64){
    // ---- build_M: M[h][p][m] = sum_j Wq[h][p][j]*Wk[h][m][j], stored Mb[p][h*128+m]
    const int h = b >> 3, pg = b & 7, p0 = pg*16;
    const float* wk = Wk + (size_t)h*16384;
    const float* wq = Wq + ((size_t)h*128 + p0)*128;
    const int m = t & 127, half = t >> 7;
    float acc[8] = {0,0,0,0,0,0,0,0};
    for (int jc = 0; jc < 4; ++jc){
      __syncthreads();
      #pragma unroll
      for (int i = 0; i < 4; ++i){
        int g = t + 256*i;
        int mm = g >> 3, j0 = (g & 7)*4;
        float4 v = *(const float4*)(wk + mm*128 + jc*32 + j0);
        float* d = &WkL[mm*33 + j0];
        d[0] = v.x; d[1] = v.y; d[2] = v.z; d[3] = v.w;
      }
      {
        int e = t*2;
        int pr = e >> 5, jj = e & 31;
        float2 v = *(const float2*)(wq + pr*128 + jc*32 + jj);
        WqL[pr*33 + jj] = v.x; WqL[pr*33 + jj + 1] = v.y;
      }
      __syncthreads();
      for (int j = 0; j < 32; ++j){
        float wkv = WkL[m*33 + j];
        #pragma unroll
        for (int r = 0; r < 8; ++r)
          acc[r] = fmaf(WqL[(half*8 + r)*33 + j], wkv, acc[r]);
      }
    }
    #pragma unroll
    for (int r = 0; r < 8; ++r)
      Mb[(size_t)(p0 + half*8 + r)*1024 + h*128 + m] = acc[r];
  } else if (b < 72){
    // ---- build_bias
    if (t < 128){
      int h = b - 64, m = t;
      const float* wkr = Wk + ((size_t)h*128 + m)*128;
      const float* wqr = Wq + ((size_t)h*128 + m)*128;
      const float* bqr = bq + h*128;
      const float* bkr = bk + h*128;
      float c = 0.f, u = 0.f;
      for (int j = 0; j < 128; ++j){
        c = fmaf(wkr[j], bqr[j], c);
        u = fmaf(wqr[j], bkr[j], u);
      }
      cvec[h*128 + m] = c;
      uvec[h*128 + m] = u;
      if (m == 0){
        float s = 0.f;
        for (int j = 0; j < 128; ++j) s = fmaf(bqr[j], bkr[j], s);
        sv[h] = s;
      }
    }
  } else if (b < 328){
    // ---- Wo pack: K=1024, C=128, ctn=8
    if (t < 64) frag_pack_body(Wo, Wp, 128, 8, b - 72, t);
  } else {
    // ---- count_edges
    int e = (b - 328)*256 + t;
    if (e < E) atomicAdd(&counts[av[e]], 1);
  }
}

// ---------------- PREP2: scan_offsets(256-thr) | Mb-pack | scatter_aq
__global__ __launch_bounds__(256) void prep2(
    const int* __restrict__ counts, int* __restrict__ offsets, int N,
    const float* __restrict__ Mb, uint4* __restrict__ Mp,
    const int* __restrict__ pk, const int* __restrict__ pv,
    const float* __restrict__ ast, float* __restrict__ aq,
    ushort* __restrict__ aqh, ushort* __restrict__ aql, int n_map)
{
  __shared__ int pa[256];
  __shared__ int pb[256];
  const int b = blockIdx.x, t = threadIdx.x;
  if (b == 0){
    // ---- exclusive scan of counts -> offsets (one block, 256 threads)
    const int CH = (N + 255) >> 8;
    int b0 = t*CH, e0 = b0 + CH;
    if (b0 > N) b0 = N;
    if (e0 > N) e0 = N;
    int s = 0;
    for (int i = b0; i < e0; ++i) s += counts[i];
    pa[t] = s;
    __syncthreads();
    int* src = pa; int* dst = pb;
    for (int off = 1; off < 256; off <<= 1){
      int v = src[t];
      if (t >= off) v += src[t - off];
      __syncthreads();
      dst[t] = v;
      __syncthreads();
      int* tmp = src; src = dst; dst = tmp;
    }
    int run = src[t] - s;
    for (int i = b0; i < e0; ++i){ offsets[i] = run; run += counts[i]; }
    if (t == 255) offsets[N] = src[255];
  } else if (b < 257){
    // ---- Mb pack: K=128, C=1024, ctn=64
    if (t < 64) frag_pack_body(Mb, Mp, 1024, 64, b - 1, t);
  } else {
    // ---- scatter_aq, 4 mappings per block
    int i = (b - 257)*4 + (t >> 6);
    int lane = t & 63;
    if (i < n_map){
      int k = pk[i], src = pv[i];
      float2 v = *(const float2*)(ast + (size_t)src*128 + 2*lane);
      *(float2*)(aq + (size_t)k*128 + 2*lane) = v;
      ushort h0 = f2b(v.x), h1 = f2b(v.y);
      ushort l0 = f2b(v.x - b2f(h0)), l1 = f2b(v.y - b2f(h1));
      *(uint*)(aqh + (size_t)k*128 + 2*lane) = (uint)h0 | ((uint)h1 << 16);
      *(uint*)(aql + (size_t)k*128 + 2*lane) = (uint)l0 | ((uint)l1 << 16);
    }
  }
}

// ---------------- PREP3: qb_kernel | fill_edges
__global__ __launch_bounds__(256) void prep3(
    const float* __restrict__ aq, const float* __restrict__ uvec, const float* __restrict__ sv,
    float* __restrict__ qb, const int* __restrict__ av, const int* __restrict__ akey,
    const int* __restrict__ offsets, int* __restrict__ cursor, int* __restrict__ ridx,
    int N, int E)
{
  const int b = blockIdx.x, t = threadIdx.x;
  const int nqb = (N + 3) >> 2;
  if (b < nqb){
    int n = b*4 + (t >> 6);
    int lane = t & 63;
    if (n < N){
      int h = lane >> 3, g = lane & 7;
      const float* ar = aq + (size_t)n*128 + g*16;
      const float* ur = uvec + h*128 + g*16;
      float dot = 0.f;
      #pragma unroll
      for (int k = 0; k < 16; ++k) dot = fmaf(ar[k], ur[k], dot);
      dot += __shfl_xor(dot, 1);
      dot += __shfl_xor(dot, 2);
      dot += __shfl_xor(dot, 4);
      if (g == 0) qb[(size_t)n*8 + h] = dot + sv[h];
    }
  } else {
    int e = (b - nqb)*256 + t;
    if (e < E){
      int seg = av[e];
      int pos = offsets[seg] + atomicAdd(&cursor[seg], 1);
      ridx[pos] = akey[e];
    }
  }
}

// ---------------- K3: qt = aq*Mb + cvec via split-bf16 MFMA (3 passes).
__global__ __launch_bounds__(256, 1) void qt_mfma(const ushort* __restrict__ aqh, const ushort* __restrict__ aql,
                                                  const uint4* __restrict__ Mp, const float* __restrict__ cvec,
                                                  bf16* __restrict__ qt, int N){
  const int l = threadIdx.x & 63, w = threadIdx.x >> 6;
  const int lr = l & 15, lk = l >> 4;
  const int r0 = blockIdx.x*128 + w*32;
  int ra = r0 + lr;      if (ra > N-1) ra = N-1;
  int rb = r0 + 16 + lr; if (rb > N-1) rb = N-1;

  bf16x8 Ah0[4], Al0[4], Ah1[4], Al1[4];
  #pragma unroll
  for (int ks = 0; ks < 4; ++ks){
    Ah0[ks] = *(const bf16x8*)(aqh + (size_t)ra*128 + lk*8 + ks*32);
    Al0[ks] = *(const bf16x8*)(aql + (size_t)ra*128 + lk*8 + ks*32);
    Ah1[ks] = *(const bf16x8*)(aqh + (size_t)rb*128 + lk*8 + ks*32);
    Al1[ks] = *(const bf16x8*)(aql + (size_t)rb*128 + lk*8 + ks*32);
  }
  const uint4* pw = Mp + l;

  bf16x8 Ba[8], Bb[8];   // [ks*2 + {hi,lo}]
  auto LDB = [&](int ct, bf16x8* B){
    #pragma unroll
    for (int ks = 0; ks < 4; ++ks){
      const uint4* q = pw + ((size_t)(ks*64 + ct)*2)*64;
      B[ks*2]   = *(const bf16x8*)q;
      B[ks*2+1] = *(const bf16x8*)(q + 64);
    }
  };
  auto DO = [&](int ct, bf16x8* B){
    f32x4 a0 = {0.f,0.f,0.f,0.f}, a1 = {0.f,0.f,0.f,0.f};
    #pragma unroll
    for (int ks = 0; ks < 4; ++ks){
      a0 = __builtin_amdgcn_mfma_f32_16x16x32_bf16(Ah0[ks], B[2*ks],   a0, 0, 0, 0);
      a1 = __builtin_amdgcn_mfma_f32_16x16x32_bf16(Ah1[ks], B[2*ks],   a1, 0, 0, 0);
      a0 = __builtin_amdgcn_mfma_f32_16x16x32_bf16(Al0[ks], B[2*ks],   a0, 0, 0, 0);
      a1 = __builtin_amdgcn_mfma_f32_16x16x32_bf16(Al1[ks], B[2*ks],   a1, 0, 0, 0);
      a0 = __builtin_amdgcn_mfma_f32_16x16x32_bf16(Ah0[ks], B[2*ks+1], a0, 0, 0, 0);
      a1 = __builtin_amdgcn_mfma_f32_16x16x32_bf16(Ah1[ks], B[2*ks+1], a1, 0, 0, 0);
    }
    const int cc = ct*16 + lr;
    const float bv = cvec[cc];
    #pragma unroll
    for (int i = 0; i < 4; ++i){
      int rr0 = r0 + lk*4 + i;
      if (rr0 < N) ((ushort*)qt)[(size_t)rr0*1024 + cc] = f2b(a0[i] + bv);
      int rr1 = r0 + 16 + lk*4 + i;
      if (rr1 < N) ((ushort*)qt)[(size_t)rr1*1024 + cc] = f2b(a1[i] + bv);
    }
  };

  LDB(0, Ba);
  for (int ct = 0; ct < 64; ct += 2){
    LDB(ct + 1, Bb);
    DO(ct, Ba);
    if (ct + 2 < 64) LDB(ct + 2, Ba);
    DO(ct + 1, Bb);
  }
}

// ---------------- K6: per-segment attention v5. 1 wave = 1 segment.
// Round-3 straight-line structure (unconditional clamped prefetch, no guards, no readlane —
// that variant allocated cleanly with zero scratch) PLUS __launch_bounds__(256,4): the
// 128-VGPR target stops the scheduler from sinking the prefetch loads next to their uses,
// keeping the 6-edge pipeline (3 pair-buffers, 12 VMEM in flight) live in registers.
__global__ __launch_bounds__(256, 4) void seg_attn(
    const bf16* __restrict__ qt, const float* __restrict__ qb,
    const int* __restrict__ offsets, const int* __restrict__ ridx,
    const float* __restrict__ ast, bf16* __restrict__ ho, int N)
{
  const int wid  = threadIdx.x >> 6;
  const int lane = threadIdx.x & 63;
  const int n = blockIdx.x*4 + wid;
  if (n >= N) return;
  const int beg = __builtin_amdgcn_readfirstlane(offsets[n]);
  const int end = __builtin_amdgcn_readfirstlane(offsets[n+1]);
  const int deg = end - beg;
  const int grp = lane >> 4, d4 = lane & 15;
  const int h0 = 2*grp, h1 = 2*grp + 1;

  // q fragments: 8 dims of heads h0,h1 at dims d4*8..+8
  const ushort* qtp = (const ushort*)qt + (size_t)n*1024 + d4*8;
  const uint4 Qa = *(const uint4*)(qtp + h0*128);
  const uint4 Qb = *(const uint4*)(qtp + h1*128);
  const float4 q0lo = make_float4(blo(Qa.x), bhi(Qa.x), blo(Qa.y), bhi(Qa.y));
  const float4 q0hi = make_float4(blo(Qa.z), bhi(Qa.z), blo(Qa.w), bhi(Qa.w));
  const float4 q1lo = make_float4(blo(Qb.x), bhi(Qb.x), blo(Qb.y), bhi(Qb.y));
  const float4 q1hi = make_float4(blo(Qb.z), bhi(Qb.z), blo(Qb.w), bhi(Qb.w));
  const float SC = 0.12751744886681336f;           // log2(e)/sqrt(128)
  const float qs0 = qb[(size_t)n*8 + h0] * SC;
  const float qs1 = qb[(size_t)n*8 + h1] * SC;

  const int* rp = ridx + beg;

  float den0 = 0.f, den1 = 0.f;
  float4 x0lo = make_float4(0,0,0,0), x0hi = x0lo, x1lo = x0lo, x1hi = x0lo;

  if (deg > 0){
#define LOADP(Pa0, Pa1, Pb0, Pb1, base) do { \
    int iA = (base) < deg ? (base) : deg-1; \
    int iB = (base)+1 < deg ? (base)+1 : deg-1; \
    const float4* pA = (const float4*)(ast + (size_t)rp[iA]*128 + d4*8); \
    const float4* pB = (const float4*)(ast + (size_t)rp[iB]*128 + d4*8); \
    Pa0 = pA[0]; Pa1 = pA[1]; Pb0 = pB[0]; Pb1 = pB[1]; } while(0)

#define C1(A0, A1) do { \
    float s0, s1; \
    s0 = A0.x*q0lo.x; s0 = fmaf(A0.y, q0lo.y, s0); s0 = fmaf(A0.z, q0lo.z, s0); s0 = fmaf(A0.w, q0lo.w, s0); \
    s0 = fmaf(A1.x, q0hi.x, s0); s0 = fmaf(A1.y, q0hi.y, s0); s0 = fmaf(A1.z, q0hi.z, s0); s0 = fmaf(A1.w, q0hi.w, s0); \
    s1 = A0.x*q1lo.x; s1 = fmaf(A0.y, q1lo.y, s1); s1 = fmaf(A0.z, q1lo.z, s1); s1 = fmaf(A0.w, q1lo.w, s1); \
    s1 = fmaf(A1.x, q1hi.x, s1); s1 = fmaf(A1.y, q1hi.y, s1); s1 = fmaf(A1.z, q1hi.z, s1); s1 = fmaf(A1.w, q1hi.w, s1); \
    s0 = row16_sum(s0); s1 = row16_sum(s1); \
    const float p0 = exp2f(fmaf(s0, SC, qs0)); \
    const float p1 = exp2f(fmaf(s1, SC, qs1)); \
    den0 += p0; den1 += p1; \
    x0lo.x = fmaf(p0, A0.x, x0lo.x); x0lo.y = fmaf(p0, A0.y, x0lo.y); \
    x0lo.z = fmaf(p0, A0.z, x0lo.z); x0lo.w = fmaf(p0, A0.w, x0lo.w); \
    x0hi.x = fmaf(p0, A1.x, x0hi.x); x0hi.y = fmaf(p0, A1.y, x0hi.y); \
    x0hi.z = fmaf(p0, A1.z, x0hi.z); x0hi.w = fmaf(p0, A1.w, x0hi.w); \
    x1lo.x = fmaf(p1, A0.x, x1lo.x); x1lo.y = fmaf(p1, A0.y, x1lo.y); \
    x1lo.z = fmaf(p1, A0.z, x1lo.z); x1lo.w = fmaf(p1, A0.w, x1lo.w); \
    x1hi.x = fmaf(p1, A1.x, x1hi.x); x1hi.y = fmaf(p1, A1.y, x1hi.y); \
    x1hi.z = fmaf(p1, A1.z, x1hi.z); x1hi.w = fmaf(p1, A1.w, x1hi.w); \
  } while(0)

    float4 P0a0, P0a1, P0b0, P0b1;
    float4 P1a0, P1a1, P1b0, P1b1;
    float4 P2a0, P2a1, P2b0, P2b1;
    LOADP(P0a0, P0a1, P0b0, P0b1, 0);
    LOADP(P1a0, P1a1, P1b0, P1b1, 2);
    LOADP(P2a0, P2a1, P2b0, P2b1, 4);
    int e = 0;
    for (; e + 5 < deg; e += 6){
      C1(P0a0, P0a1); C1(P0b0, P0b1); LOADP(P0a0, P0a1, P0b0, P0b1, e + 6);
      C1(P1a0, P1a1); C1(P1b0, P1b1); LOADP(P1a0, P1a1, P1b0, P1b1, e + 8);
      C1(P2a0, P2a1); C1(P2b0, P2b1); LOADP(P2a0, P2a1, P2b0, P2b1, e + 10);
    }
    const int t = deg - e;   // 1..6
    if (t >= 1) C1(P0a0, P0a1);
    if (t >= 2) C1(P0b0, P0b1);
    if (t >= 3) C1(P1a0, P1a1);
    if (t >= 4) C1(P1b0, P1b1);
    if (t >= 5) C1(P2a0, P2a1);
    if (t >= 6) C1(P2b0, P2b1);
#undef C1
#undef LOADP
  }
  const float r0v = (deg > 0) ? (1.f / den0) : 0.f;
  const float r1v = (deg > 0) ? (1.f / den1) : 0.f;

  uint4 o0, o1;
  o0.x = pack2(x0lo.x*r0v, x0lo.y*r0v); o0.y = pack2(x0lo.z*r0v, x0lo.w*r0v);
  o0.z = pack2(x0hi.x*r0v, x0hi.y*r0v); o0.w = pack2(x0hi.z*r0v, x0hi.w*r0v);
  o1.x = pack2(x1lo.x*r1v, x1lo.y*r1v); o1.y = pack2(x1lo.z*r1v, x1lo.w*r1v);
  o1.z = pack2(x1hi.x*r1v, x1hi.y*r1v); o1.w = pack2(x1hi.z*r1v, x1hi.w*r1v);
  ushort* hb = (ushort*)ho + (size_t)n*1024 + d4*8;
  *(uint4*)(hb + h0*128) = o0;
  *(uint4*)(hb + h1*128) = o1;
}

// ---------------- K5: out[n][c] = sum_k ho[n][k]*Wo[k][c] + bo[c]  via bf16 MFMA, split-Wo.
__global__ __launch_bounds__(256, 1) void out_mfma(const bf16* __restrict__ ho, const uint4* __restrict__ Wp,
                                                   const float* __restrict__ bo, float* __restrict__ out, int N){
  const int l = threadIdx.x & 63, w = threadIdx.x >> 6;
  const int lr = l & 15, lk = l >> 4;
  const int r0 = blockIdx.x*128 + w*32;
  int ra = r0 + lr;      if (ra > N-1) ra = N-1;
  int rb = r0 + 16 + lr; if (rb > N-1) rb = N-1;
  const bf16* pa = ho + (size_t)ra*1024 + lk*8;
  const bf16* pb = ho + (size_t)rb*1024 + lk*8;
  const uint4* pw = Wp + l;

  f32x4 acc[2][8];
  #pragma unroll
  for (int i = 0; i < 2; ++i)
    #pragma unroll
    for (int c = 0; c < 8; ++c)
      #pragma unroll
      for (int j = 0; j < 4; ++j) acc[i][c][j] = 0.f;

  bf16x8 Aa[2], Ab[2], Ba[16], Bb[16];

  auto LD = [&](int ks, bf16x8* A, bf16x8* B){
    A[0] = *(const bf16x8*)(pa + ks*32);
    A[1] = *(const bf16x8*)(pb + ks*32);
    const uint4* q = pw + (size_t)ks*1024;
    #pragma unroll
    for (int u = 0; u < 16; ++u) B[u] = *(const bf16x8*)(q + (size_t)u*64);
  };
  auto MM = [&](bf16x8* A, bf16x8* B){
    #pragma unroll
    for (int c = 0; c < 8; ++c){
      acc[0][c] = __builtin_amdgcn_mfma_f32_16x16x32_bf16(A[0], B[2*c],   acc[0][c], 0, 0, 0);
      acc[1][c] = __builtin_amdgcn_mfma_f32_16x16x32_bf16(A[1], B[2*c],   acc[1][c], 0, 0, 0);
      acc[0][c] = __builtin_amdgcn_mfma_f32_16x16x32_bf16(A[0], B[2*c+1], acc[0][c], 0, 0, 0);
      acc[1][c] = __builtin_amdgcn_mfma_f32_16x16x32_bf16(A[1], B[2*c+1], acc[1][c], 0, 0, 0);
    }
  };

  LD(0, Aa, Ba);
  for (int ks = 0; ks < 32; ks += 2){
    LD(ks + 1, Ab, Bb);
    MM(Aa, Ba);
    if (ks + 2 < 32) LD(ks + 2, Aa, Ba);
    MM(Ab, Bb);
  }

  #pragma unroll
  for (int c = 0; c < 8; ++c){
    float bv = bo[c*16 + lr];
    #pragma unroll
    for (int rt = 0; rt < 2; ++rt){
      #pragma unroll
      for (int i = 0; i < 4; ++i){
        int rr = r0 + rt*16 + lk*4 + i;
        if (rr < N) out[(size_t)rr*128 + c*16 + lr] = acc[rt][c][i] + bv;
      }
    }
  }
}

extern "C" void kernel_launch(void* const* d_in, const int* in_sizes, int n_in,
                              void* d_out, int out_size, void* d_ws, size_t ws_size,
                              hipStream_t stream) {
  const float* ast = (const float*)d_in[0];
  const float* Wq  = (const float*)d_in[1];
  const float* bq  = (const float*)d_in[2];
  const float* Wk  = (const float*)d_in[3];
  const float* bk  = (const float*)d_in[4];
  const float* Wo  = (const float*)d_in[5];
  const float* bo  = (const float*)d_in[6];
  const int* ast_key   = (const int*)d_in[7];
  const int* ast_value = (const int*)d_in[8];
  const int* pdg_key   = (const int*)d_in[9];
  const int* pdg_value = (const int*)d_in[10];
  const int E     = in_sizes[7];
  const int n_map = in_sizes[9];
  const int N     = out_size / 128;
  float* out = (float*)d_out;   // reference output dtype is float32

  char* w = (char*)d_ws;
  auto carve = [&](size_t bytes)->char*{
    char* p = w; w += (bytes + 255) & ~size_t(255); return p;
  };
  // NOTE: aq/aqh/aql adjacent (one memset); counts/cursor adjacent (one memset).
  bf16*  qt      = (bf16*) carve((size_t)N*1024*2);
  float* aq      = (float*)carve((size_t)N*128*4);
  ushort* aqh    = (ushort*)carve((size_t)N*128*2);
  ushort* aql    = (ushort*)carve((size_t)N*128*2);
  float* Mb      = (float*)carve((size_t)128*1024*4);
  float* cvec    = (float*)carve(1024*4);
  float* uvec    = (float*)carve(1024*4);
  float* sv      = (float*)carve(8*4);
  float* qb      = (float*)carve((size_t)N*8*4);
  int*   counts  = (int*)  carve((size_t)N*4);
  int*   cursor  = (int*)  carve((size_t)N*4);
  int*   offsets = (int*)  carve((size_t)(N+1)*4);
  int*   ridx    = (int*)  carve((size_t)E*4);
  bf16*  ho      = (bf16*) carve((size_t)N*1024*2);
  uint4* Wp      = (uint4*)carve((size_t)256*2*64*16);   // 512 KB packed WoHi/WoLo frags
  uint4* Mp      = (uint4*)carve((size_t)256*2*64*16);   // 512 KB packed MbHi/MbLo frags
  (void)ws_size; (void)n_in;

  hipMemsetAsync(aq,     0, (size_t)N*128*8, stream);    // aq + aqh + aql (contiguous)
  hipMemsetAsync(counts, 0, (size_t)N*8, stream);        // counts + cursor (contiguous)

  const int nb_cnt  = (E + 255)/256;
  const int nb_sca  = (n_map + 3)/4;
  const int nb_qb   = (N + 3)/4;

  prep1<<<328 + nb_cnt, 256, 0, stream>>>(Wq, Wk, bq, bk, Wo, ast_value, Mb, cvec, uvec, sv, Wp, counts, E);
  prep2<<<257 + nb_sca, 256, 0, stream>>>(counts, offsets, N, Mb, Mp, pdg_key, pdg_value, ast, aq, aqh, aql, n_map);
  qt_mfma<<<(N + 127)/128, 256, 0, stream>>>(aqh, aql, Mp, cvec, qt, N);
  prep3<<<nb_qb + nb_cnt, 256, 0, stream>>>(aq, uvec, sv, qb, ast_value, ast_key, offsets, cursor, ridx, N, E);
  seg_attn<<<(N + 3)/4, 256, 0, stream>>>(qt, qb, offsets, ridx, ast, ho, N);
  out_mfma<<<(N + 127)/128, 256, 0, stream>>>(ho, Wp, bo, out, N);
}